// Round 2
// baseline (138.022 us; speedup 1.0000x reference)
//
#include <hip/hip_runtime.h>
#include <math.h>

#define EPSN 1e-4f
#define SEQ 2304

using bf16x8 = __attribute__((ext_vector_type(8))) short;
using f32x4  = __attribute__((ext_vector_type(4))) float;

__device__ inline unsigned short f2bf(float x) {
    union { float f; unsigned u; } c; c.f = x;
    unsigned u = c.u;
    u += 0x7fffu + ((u >> 16) & 1u);
    return (unsigned short)(u >> 16);
}

// HW packed f32->bf16 (RNE), gfx950.
__device__ inline unsigned cvt_pk_bf16(float lo, float hi) {
    unsigned r;
    asm("v_cvt_pk_bf16_f32 %0, %1, %2" : "=v"(r) : "v"(lo), "v"(hi));
    return r;
}

// ---------------- Kernel 1: prep = weight-norm (blocks 0..255, 4 rows each) + x-transpose ----------------
__global__ __launch_bounds__(256) void prep_kernel(const float* __restrict__ w_qkv,
                                                   const float* __restrict__ w_out,
                                                   const float* __restrict__ x,
                                                   unsigned short* __restrict__ wqb,
                                                   unsigned short* __restrict__ wob,
                                                   unsigned short* __restrict__ xt) {
    __shared__ __align__(16) unsigned short T[64][80];
    int bid = blockIdx.x;
    if (bid < 256) {
        // w_eff[o,i] = w[o,i] / (16*EPS + ||w[o]||), stored bf16; one row per wave
        int wave = threadIdx.x >> 6, lane = threadIdx.x & 63;
        int row = bid * 4 + wave;
        const float* src;
        unsigned short* dst;
        if (row < 768) { src = w_qkv + (size_t)row * 256; dst = wqb + (size_t)row * 256; }
        else           { src = w_out + (size_t)(row - 768) * 256; dst = wob + (size_t)(row - 768) * 256; }
        float4 v = *(const float4*)&src[lane * 4];
        float ss = v.x * v.x + v.y * v.y + v.z * v.z + v.w * v.w;
        for (int off = 32; off > 0; off >>= 1) ss += __shfl_xor(ss, off, 64);
        float sc = 1.0f / (sqrtf(ss) + 16.0f * EPSN);
        unsigned p0 = (unsigned)f2bf(v.x * sc) | ((unsigned)f2bf(v.y * sc) << 16);
        unsigned p1 = (unsigned)f2bf(v.z * sc) | ((unsigned)f2bf(v.w * sc) << 16);
        *(uint2*)&dst[lane * 4] = make_uint2(p0, p1);
    } else {
        // transpose x[n][c][s] -> xt[n][s][c] bf16
        int e0 = bid - 256;            // 0..287
        int st = e0 % 36, ct = (e0 / 36) & 3, n = e0 / 144;
        int t = threadIdx.x;
#pragma unroll
        for (int p = 0; p < 4; ++p) {
            int e = t + p * 256;
            int c = e >> 4, sv = (e & 15) * 4;
            float4 v = *(const float4*)&x[(size_t)(n * 256 + ct * 64 + c) * SEQ + st * 64 + sv];
            T[sv + 0][c] = f2bf(v.x);
            T[sv + 1][c] = f2bf(v.y);
            T[sv + 2][c] = f2bf(v.z);
            T[sv + 3][c] = f2bf(v.w);
        }
        __syncthreads();
#pragma unroll
        for (int p = 0; p < 2; ++p) {
            int e = t + p * 256;
            int s = e >> 3, cb = (e & 7) * 8;
            uint4 v = *(const uint4*)&T[s][cb];
            *(uint4*)&xt[(size_t)(n * SEQ + st * 64 + s) * 256 + ct * 64 + cb] = v;
        }
    }
}

// ---------------- Kernel 2: fused QKV GEMM + d-normalize ----------------
// grid (8 heads, 36 s-tiles, 2 n); block computes 96x64 (one head's q,k,v),
// normalizes over d=32, writes qn/kn [nh][s][d], vn [nh][d][s] bf16.
// q folds softmax scale AND log2(e) so attn uses exp2 directly.
__global__ __launch_bounds__(256) void qkv_fused_kernel(const unsigned short* __restrict__ xt,
                                                        const unsigned short* __restrict__ wqb,
                                                        unsigned short* __restrict__ qn,
                                                        unsigned short* __restrict__ kn,
                                                        unsigned short* __restrict__ vn) {
    __shared__ float Cs[96][65];
    int h  = blockIdx.x;
    int st = blockIdx.y;
    int n  = blockIdx.z;
    int tid = threadIdx.x;
    int wave = tid >> 6, lane = tid & 63;
    int ln = lane & 15, quad = lane >> 4;
    const unsigned short* Abase = wqb + (size_t)(h * 96 + ln) * 256 + quad * 8;
    const unsigned short* Bbase = xt + (size_t)(n * SEQ + st * 64 + wave * 16 + ln) * 256 + quad * 8;
    f32x4 acc[6];
#pragma unroll
    for (int m = 0; m < 6; ++m) acc[m] = (f32x4){0.f, 0.f, 0.f, 0.f};
#pragma unroll
    for (int kc = 0; kc < 8; ++kc) {
        bf16x8 b = *(const bf16x8*)(Bbase + kc * 32);
#pragma unroll
        for (int m = 0; m < 6; ++m) {
            bf16x8 a = *(const bf16x8*)(Abase + (size_t)(m * 16) * 256 + kc * 32);
            acc[m] = __builtin_amdgcn_mfma_f32_16x16x32_bf16(a, b, acc[m], 0, 0, 0);
        }
    }
#pragma unroll
    for (int m = 0; m < 6; ++m)
#pragma unroll
        for (int r = 0; r < 4; ++r)
            Cs[m * 16 + quad * 4 + r][wave * 16 + ln] = acc[m][r];
    __syncthreads();
    if (tid < 192) {
        int sl = tid & 63, wh = tid >> 6;
        int s = st * 64 + sl;
        int nh = n * 8 + h;
        float v[32];
        float ss = 0.f;
#pragma unroll
        for (int d = 0; d < 32; ++d) { v[d] = Cs[3 * d + wh][sl]; ss += v[d] * v[d]; }
        float inv = 1.0f / (EPSN + sqrtf(ss * (1.0f / 32.0f)));
        // fold softmax scale (1/sqrt(32)) AND log2(e) into q so attn uses exp2
        if (wh == 0) inv *= 0.17677669529663687f * 1.4426950408889634f;
        if (wh == 2) {
            unsigned short* dst = vn + (size_t)nh * 73728 + s;
#pragma unroll
            for (int d = 0; d < 32; ++d) dst[(size_t)d * SEQ] = f2bf(v[d] * inv);
        } else {
            unsigned short* dst = (wh == 1 ? kn : qn) + (size_t)nh * 73728 + (size_t)s * 32;
            unsigned wbuf[16];
#pragma unroll
            for (int j = 0; j < 16; ++j)
                wbuf[j] = (unsigned)f2bf(v[2 * j] * inv) | ((unsigned)f2bf(v[2 * j + 1] * inv) << 16);
#pragma unroll
            for (int j = 0; j < 4; ++j) {
                uint4 t4 = make_uint4(wbuf[4 * j], wbuf[4 * j + 1], wbuf[4 * j + 2], wbuf[4 * j + 3]);
                *(uint4*)(dst + j * 8) = t4;
            }
        }
    }
}

// ---------------- Kernel 3: MFMA flash attention, NO split-K, writes y2t directly ----------------
// grid (36 q-tiles, 16 nh). Each block iterates all 36 K/V tiles, accumulating
// o0/o1/lac in registers (swapped QK layout => lac[r] holds the full row-sum for
// this lane's q row: normalization is lane-local, no cross-lane or split-K reduce).
// Epilogue routes o/l through LDS for coalesced bf16 y2t stores.
__global__ __launch_bounds__(256) void attn_mfma_kernel(const unsigned short* __restrict__ qn,
                                                        const unsigned short* __restrict__ kn,
                                                        const unsigned short* __restrict__ vn,
                                                        unsigned short* __restrict__ y2t) {
    __shared__ __align__(16) unsigned short Ks[2][64][40];
    __shared__ __align__(16) unsigned short Vs[2][32][72];
    __shared__ __align__(16) unsigned short Ps[4][16][72];
    __shared__ float Os[64][33];
    int tid = threadIdx.x;
    int wave = tid >> 6, lane = tid & 63;
    int ln = lane & 15, quad = lane >> 4;
    int qt = blockIdx.x, nh = blockIdx.y;
    int n = nh >> 3, h = nh & 7;
    const unsigned short* Qg = qn + (size_t)nh * 73728;
    const unsigned short* Kg = kn + (size_t)nh * 73728;
    const unsigned short* Vg = vn + (size_t)nh * 73728;

    bf16x8 qf = *(const bf16x8*)(Qg + (size_t)(qt * 64 + wave * 16 + ln) * 32 + quad * 8);
    bf16x8 ones;
#pragma unroll
    for (int i = 0; i < 8; ++i) ones[i] = (short)0x3F80;

    f32x4 o0 = {0.f, 0.f, 0.f, 0.f};
    f32x4 o1 = {0.f, 0.f, 0.f, 0.f};
    f32x4 lac = {0.f, 0.f, 0.f, 0.f};

    uint4 kreg = *(const uint4*)(Kg + (size_t)0 + tid * 8);
    uint4 vreg = *(const uint4*)(Vg + (size_t)(tid >> 3) * SEQ + (tid & 7) * 8);
    *(uint4*)(&Ks[0][tid >> 2][(tid & 3) * 8]) = kreg;
    *(uint4*)(&Vs[0][tid >> 3][(tid & 7) * 8]) = vreg;

    for (int i = 0; i < 36; ++i) {
        int buf = i & 1;
        if (i + 1 < 36) {   // stage next tile into registers
            int k0n = (i + 1) * 64;
            kreg = *(const uint4*)(Kg + (size_t)k0n * 32 + tid * 8);
            vreg = *(const uint4*)(Vg + (size_t)(tid >> 3) * SEQ + k0n + (tid & 7) * 8);
        }
        __syncthreads();   // buf fully written; prev-buf readers done

        const f32x4 zero = {0.f, 0.f, 0.f, 0.f};
#pragma unroll
        for (int c = 0; c < 4; ++c) {
            bf16x8 kf = *(const bf16x8*)(&Ks[buf][c * 16 + ln][quad * 8]);
            // swapped: lane holds S[q=ln][k=c*16+quad*4+r], r=0..3 contiguous
            f32x4 sc = __builtin_amdgcn_mfma_f32_16x16x32_bf16(kf, qf, zero, 0, 0, 0);
            unsigned w0 = cvt_pk_bf16(exp2f(sc[0]), exp2f(sc[1]));
            unsigned w1 = cvt_pk_bf16(exp2f(sc[2]), exp2f(sc[3]));
            *(uint2*)(&Ps[wave][ln][c * 16 + quad * 4]) = make_uint2(w0, w1);
        }
        // Ps is wave-private: lgkmcnt ordering suffices, no barrier
#pragma unroll
        for (int kc = 0; kc < 2; ++kc) {
            bf16x8 pf = *(const bf16x8*)(&Ps[wave][ln][kc * 32 + quad * 8]);
            bf16x8 v0 = *(const bf16x8*)(&Vs[buf][ln][kc * 32 + quad * 8]);
            bf16x8 v1 = *(const bf16x8*)(&Vs[buf][16 + ln][kc * 32 + quad * 8]);
            lac = __builtin_amdgcn_mfma_f32_16x16x32_bf16(pf, ones, lac, 0, 0, 0);
            o0  = __builtin_amdgcn_mfma_f32_16x16x32_bf16(pf, v0, o0, 0, 0, 0);
            o1  = __builtin_amdgcn_mfma_f32_16x16x32_bf16(pf, v1, o1, 0, 0, 0);
        }
        if (i + 1 < 36) {
            *(uint4*)(&Ks[buf ^ 1][tid >> 2][(tid & 3) * 8]) = kreg;
            *(uint4*)(&Vs[buf ^ 1][tid >> 3][(tid & 7) * 8]) = vreg;
        }
    }

    // epilogue: normalize (lane-local l) -> LDS f32 -> coalesced bf16 y2t stores
#pragma unroll
    for (int r = 0; r < 4; ++r) {
        int q = wave * 16 + quad * 4 + r;
        float inv = 1.0f / lac[r];
        Os[q][ln]      = o0[r] * inv;
        Os[q][16 + ln] = o1[r] * inv;
    }
    __syncthreads();
    {
        int q = tid >> 2, dg = tid & 3;
        const float* row = &Os[q][dg * 8];
        unsigned u0 = (unsigned)f2bf(row[0]) | ((unsigned)f2bf(row[1]) << 16);
        unsigned u1 = (unsigned)f2bf(row[2]) | ((unsigned)f2bf(row[3]) << 16);
        unsigned u2 = (unsigned)f2bf(row[4]) | ((unsigned)f2bf(row[5]) << 16);
        unsigned u3 = (unsigned)f2bf(row[6]) | ((unsigned)f2bf(row[7]) << 16);
        *(uint4*)&y2t[((size_t)(n * SEQ) + qt * 64 + q) * 256 + h * 32 + dg * 8] =
            make_uint4(u0, u1, u2, u3);
    }
}

// ---------------- Kernel 4: out GEMM (bf16 MFMA, LDS-free) + residual ----------------
// 32-row s-tiles -> 576 blocks (2/CU) for latency hiding.
__global__ __launch_bounds__(256) void out_gemm_kernel(const unsigned short* __restrict__ y2t,
                                                       const unsigned short* __restrict__ wob,
                                                       const float* __restrict__ x,
                                                       float* __restrict__ out) {
    int mt = blockIdx.x;   // 0..3
    int st = blockIdx.y;   // 0..71
    int n  = blockIdx.z;
    int tid = threadIdx.x;
    int wave = tid >> 6, lane = tid & 63;
    int ln = lane & 15, quad = lane >> 4;
    int m0 = mt * 64 + wave * 16;
    const unsigned short* Abase = wob + (size_t)(m0 + ln) * 256 + quad * 8;
    const unsigned short* Bbase = y2t + (size_t)(n * SEQ + st * 32 + ln) * 256 + quad * 8;
    f32x4 acc[2];
#pragma unroll
    for (int c = 0; c < 2; ++c) acc[c] = (f32x4){0.f, 0.f, 0.f, 0.f};
#pragma unroll
    for (int kc = 0; kc < 8; ++kc) {
        bf16x8 a = *(const bf16x8*)(Abase + kc * 32);
#pragma unroll
        for (int c = 0; c < 2; ++c) {
            bf16x8 b = *(const bf16x8*)(Bbase + (size_t)(c * 16) * 256 + kc * 32);
            acc[c] = __builtin_amdgcn_mfma_f32_16x16x32_bf16(a, b, acc[c], 0, 0, 0);
        }
    }
    const float c0f = 0.7f * 1.3130643285972254f;
    const float c1f = 0.3f * 1.3130643285972254f;
#pragma unroll
    for (int c = 0; c < 2; ++c)
#pragma unroll
        for (int r = 0; r < 4; ++r) {
            int o = m0 + quad * 4 + r;
            int s = st * 32 + c * 16 + ln;
            size_t idx = (size_t)(n * 256 + o) * SEQ + s;
            out[idx] = c0f * x[idx] + c1f * acc[c][r];
        }
}

extern "C" void kernel_launch(void* const* d_in, const int* in_sizes, int n_in,
                              void* d_out, int out_size, void* d_ws, size_t ws_size,
                              hipStream_t stream) {
    (void)in_sizes; (void)n_in; (void)out_size; (void)ws_size;
    const float* x     = (const float*)d_in[0];
    const float* w_qkv = (const float*)d_in[1];
    const float* w_out = (const float*)d_in[2];
    float* out = (float*)d_out;
    float* ws  = (float*)d_ws;
    // float offsets (10 MB total now: Opart/Lpart removed):
    unsigned short* wqb = (unsigned short*)(ws);             // 98304 f
    unsigned short* wob = (unsigned short*)(ws + 98304);     // 32768 f
    unsigned short* xt  = (unsigned short*)(ws + 131072);    // 589824 f (dead after qkv)
    unsigned short* y2t = (unsigned short*)(ws + 131072);    // alias of xt
    unsigned short* qn  = (unsigned short*)(ws + 720896);
    unsigned short* kn  = (unsigned short*)(ws + 1310720);
    unsigned short* vn  = (unsigned short*)(ws + 1900544);

    hipLaunchKernelGGL(prep_kernel, dim3(544), dim3(256), 0, stream,
                       w_qkv, w_out, x, wqb, wob, xt);
    hipLaunchKernelGGL(qkv_fused_kernel, dim3(8, 36, 2), dim3(256), 0, stream,
                       xt, wqb, qn, kn, vn);
    hipLaunchKernelGGL(attn_mfma_kernel, dim3(36, 16), dim3(256), 0, stream,
                       qn, kn, vn, y2t);
    hipLaunchKernelGGL(out_gemm_kernel, dim3(4, 72, 2), dim3(256), 0, stream,
                       y2t, wob, x, out);
}

// Round 3
// 133.714 us; speedup vs baseline: 1.0322x; 1.0322x over previous
//
#include <hip/hip_runtime.h>
#include <math.h>

#define EPSN 1e-4f
#define SEQ 2304

using bf16x8 = __attribute__((ext_vector_type(8))) short;
using f32x4  = __attribute__((ext_vector_type(4))) float;

__device__ inline unsigned short f2bf(float x) {
    union { float f; unsigned u; } c; c.f = x;
    unsigned u = c.u;
    u += 0x7fffu + ((u >> 16) & 1u);
    return (unsigned short)(u >> 16);
}

// HW packed f32->bf16 (RNE), gfx950.
__device__ inline unsigned cvt_pk_bf16(float lo, float hi) {
    unsigned r;
    asm("v_cvt_pk_bf16_f32 %0, %1, %2" : "=v"(r) : "v"(lo), "v"(hi));
    return r;
}
// gfx950 cross-row swaps. permlane32: X.lanes[32:63] <-> Y.lanes[0:31]
// => X' = [X.q0, X.q1, Y.q0, Y.q1], Y' = [X.q2, X.q3, Y.q2, Y.q3] (q = 16-lane row)
__device__ inline void permlane32_swap(unsigned &a, unsigned &b) {
    asm("v_permlane32_swap_b32 %0, %1" : "+v"(a), "+v"(b));
}
// permlane16: X rows{1,3} <-> Y rows{0,2} => X' = [X0,Y0,X2,Y2], Y' = [X1,Y1,X3,Y3]
__device__ inline void permlane16_swap(unsigned &a, unsigned &b) {
    asm("v_permlane16_swap_b32 %0, %1" : "+v"(a), "+v"(b));
}

// ---------------- Kernel 1: prep = weight-norm (blocks 0..255, 4 rows each) + x-transpose ----------------
__global__ __launch_bounds__(256) void prep_kernel(const float* __restrict__ w_qkv,
                                                   const float* __restrict__ w_out,
                                                   const float* __restrict__ x,
                                                   unsigned short* __restrict__ wqb,
                                                   unsigned short* __restrict__ wob,
                                                   unsigned short* __restrict__ xt) {
    __shared__ __align__(16) unsigned short T[64][80];
    int bid = blockIdx.x;
    if (bid < 256) {
        int wave = threadIdx.x >> 6, lane = threadIdx.x & 63;
        int row = bid * 4 + wave;
        const float* src;
        unsigned short* dst;
        if (row < 768) { src = w_qkv + (size_t)row * 256; dst = wqb + (size_t)row * 256; }
        else           { src = w_out + (size_t)(row - 768) * 256; dst = wob + (size_t)(row - 768) * 256; }
        float4 v = *(const float4*)&src[lane * 4];
        float ss = v.x * v.x + v.y * v.y + v.z * v.z + v.w * v.w;
        for (int off = 32; off > 0; off >>= 1) ss += __shfl_xor(ss, off, 64);
        float sc = 1.0f / (sqrtf(ss) + 16.0f * EPSN);
        unsigned p0 = (unsigned)f2bf(v.x * sc) | ((unsigned)f2bf(v.y * sc) << 16);
        unsigned p1 = (unsigned)f2bf(v.z * sc) | ((unsigned)f2bf(v.w * sc) << 16);
        *(uint2*)&dst[lane * 4] = make_uint2(p0, p1);
    } else {
        int e0 = bid - 256;            // 0..287
        int st = e0 % 36, ct = (e0 / 36) & 3, n = e0 / 144;
        int t = threadIdx.x;
#pragma unroll
        for (int p = 0; p < 4; ++p) {
            int e = t + p * 256;
            int c = e >> 4, sv = (e & 15) * 4;
            float4 v = *(const float4*)&x[(size_t)(n * 256 + ct * 64 + c) * SEQ + st * 64 + sv];
            T[sv + 0][c] = f2bf(v.x);
            T[sv + 1][c] = f2bf(v.y);
            T[sv + 2][c] = f2bf(v.z);
            T[sv + 3][c] = f2bf(v.w);
        }
        __syncthreads();
#pragma unroll
        for (int p = 0; p < 2; ++p) {
            int e = t + p * 256;
            int s = e >> 3, cb = (e & 7) * 8;
            uint4 v = *(const uint4*)&T[s][cb];
            *(uint4*)&xt[(size_t)(n * SEQ + st * 64 + s) * 256 + ct * 64 + cb] = v;
        }
    }
}

// ---------------- Kernel 2: fused QKV GEMM + d-normalize ----------------
// v now routed through LDS -> coalesced uint4 stores (was 2048 scalar b16 global stores/block).
__global__ __launch_bounds__(256) void qkv_fused_kernel(const unsigned short* __restrict__ xt,
                                                        const unsigned short* __restrict__ wqb,
                                                        unsigned short* __restrict__ qn,
                                                        unsigned short* __restrict__ kn,
                                                        unsigned short* __restrict__ vn) {
    __shared__ float Cs[96][65];
    __shared__ __align__(16) unsigned short Vls[32][72];
    int h  = blockIdx.x;
    int st = blockIdx.y;
    int n  = blockIdx.z;
    int tid = threadIdx.x;
    int wave = tid >> 6, lane = tid & 63;
    int ln = lane & 15, quad = lane >> 4;
    const unsigned short* Abase = wqb + (size_t)(h * 96 + ln) * 256 + quad * 8;
    const unsigned short* Bbase = xt + (size_t)(n * SEQ + st * 64 + wave * 16 + ln) * 256 + quad * 8;
    f32x4 acc[6];
#pragma unroll
    for (int m = 0; m < 6; ++m) acc[m] = (f32x4){0.f, 0.f, 0.f, 0.f};
#pragma unroll
    for (int kc = 0; kc < 8; ++kc) {
        bf16x8 b = *(const bf16x8*)(Bbase + kc * 32);
#pragma unroll
        for (int m = 0; m < 6; ++m) {
            bf16x8 a = *(const bf16x8*)(Abase + (size_t)(m * 16) * 256 + kc * 32);
            acc[m] = __builtin_amdgcn_mfma_f32_16x16x32_bf16(a, b, acc[m], 0, 0, 0);
        }
    }
#pragma unroll
    for (int m = 0; m < 6; ++m)
#pragma unroll
        for (int r = 0; r < 4; ++r)
            Cs[m * 16 + quad * 4 + r][wave * 16 + ln] = acc[m][r];
    __syncthreads();
    int nh = n * 8 + h;
    if (tid < 192) {
        int sl = tid & 63, wh = tid >> 6;
        int s = st * 64 + sl;
        float v[32];
        float ss = 0.f;
#pragma unroll
        for (int d = 0; d < 32; ++d) { v[d] = Cs[3 * d + wh][sl]; ss += v[d] * v[d]; }
        float inv = 1.0f / (EPSN + sqrtf(ss * (1.0f / 32.0f)));
        // fold softmax scale (1/sqrt(32)) AND log2(e) into q so attn uses exp2
        if (wh == 0) inv *= 0.17677669529663687f * 1.4426950408889634f;
        if (wh == 2) {
#pragma unroll
            for (int d = 0; d < 32; ++d) Vls[d][sl] = f2bf(v[d] * inv);
        } else {
            unsigned short* dst = (wh == 1 ? kn : qn) + (size_t)nh * 73728 + (size_t)s * 32;
            unsigned wbuf[16];
#pragma unroll
            for (int j = 0; j < 16; ++j)
                wbuf[j] = (unsigned)f2bf(v[2 * j] * inv) | ((unsigned)f2bf(v[2 * j + 1] * inv) << 16);
#pragma unroll
            for (int j = 0; j < 4; ++j) {
                uint4 t4 = make_uint4(wbuf[4 * j], wbuf[4 * j + 1], wbuf[4 * j + 2], wbuf[4 * j + 3]);
                *(uint4*)(dst + j * 8) = t4;
            }
        }
    }
    __syncthreads();
    {
        int d = tid >> 3, sj = (tid & 7) * 8;
        uint4 t4 = *(const uint4*)&Vls[d][sj];
        *(uint4*)&vn[(size_t)nh * 73728 + (size_t)d * SEQ + st * 64 + sj] = t4;
    }
}

// ---------------- Kernel 3: MFMA flash attention, in-block split-K=2, permlane P-redistribute ----------------
// 512 threads = 2 k-groups x 4 q-subtiles. Each group owns half the K-range with its
// own K/V double-buffer. P never touches LDS: QK fragment (P[q=ln][k=c*16+quad*4+r])
// is rearranged to the PV A-fragment (P[q=ln][k=quad*8+j]) with permlane32/16 swaps
// (movement is only across 16-lane rows, ln preserved). Epilogue: LDS reduce of the
// two k-groups' (o,l), normalize, coalesced bf16 y2t store.
__global__ __launch_bounds__(512) void attn_mfma_kernel(const unsigned short* __restrict__ qn,
                                                        const unsigned short* __restrict__ kn,
                                                        const unsigned short* __restrict__ vn,
                                                        unsigned short* __restrict__ y2t) {
    __shared__ __align__(16) unsigned char SM[38912];
    unsigned short (*Ks)[64][40] = (unsigned short (*)[64][40])SM;            // [4] = [kg*2+buf]
    unsigned short (*Vs)[32][72] = (unsigned short (*)[32][72])(SM + 20480);  // [4]
    int tid = threadIdx.x;
    int wave = tid >> 6, lane = tid & 63;
    int ln = lane & 15, quad = lane >> 4;
    int kg = wave >> 2, wq = wave & 3;
    // XCD-aware swizzle: each XCD sees only 2 heads' K/V (576 = 8 * 72, bijective)
    int bid = blockIdx.x;
    int xcd = bid & 7, bi = bid >> 3;
    int nh = xcd * 2 + (bi >= 36);
    int qt = (bi >= 36) ? bi - 36 : bi;
    int n = nh >> 3, h = nh & 7;
    const unsigned short* Qg = qn + (size_t)nh * 73728;
    const unsigned short* Kg = kn + (size_t)nh * 73728;
    const unsigned short* Vg = vn + (size_t)nh * 73728;

    bf16x8 qf = *(const bf16x8*)(Qg + (size_t)(qt * 64 + wq * 16 + ln) * 32 + quad * 8);
    bf16x8 ones;
#pragma unroll
    for (int i = 0; i < 8; ++i) ones[i] = (short)0x3F80;

    f32x4 o0 = {0.f, 0.f, 0.f, 0.f};
    f32x4 o1 = {0.f, 0.f, 0.f, 0.f};
    f32x4 lac = {0.f, 0.f, 0.f, 0.f};

    int ts = tid & 255;          // staging index within k-group (kg == tid>>8)
    int kg2 = kg * 2;
    int s0 = kg * 18 * 64;       // group's first s
    uint4 kreg = *(const uint4*)(Kg + (size_t)s0 * 32 + ts * 8);
    uint4 vreg = *(const uint4*)(Vg + (size_t)(ts >> 3) * SEQ + s0 + (ts & 7) * 8);
    *(uint4*)(&Ks[kg2][ts >> 2][(ts & 3) * 8]) = kreg;
    *(uint4*)(&Vs[kg2][ts >> 3][(ts & 7) * 8]) = vreg;

    for (int i = 0; i < 18; ++i) {
        int buf = i & 1;
        if (i + 1 < 18) {   // stage next tile into registers
            int sn = s0 + (i + 1) * 64;
            kreg = *(const uint4*)(Kg + (size_t)sn * 32 + ts * 8);
            vreg = *(const uint4*)(Vg + (size_t)(ts >> 3) * SEQ + sn + (ts & 7) * 8);
        }
        __syncthreads();   // buf fully written; prev-buf readers done

        const f32x4 zero = {0.f, 0.f, 0.f, 0.f};
        unsigned w[4][2];
#pragma unroll
        for (int c = 0; c < 4; ++c) {
            bf16x8 kf = *(const bf16x8*)(&Ks[kg2 + buf][c * 16 + ln][quad * 8]);
            // swapped: lane holds S[q=ln][k=c*16+quad*4+r]
            f32x4 sc = __builtin_amdgcn_mfma_f32_16x16x32_bf16(kf, qf, zero, 0, 0, 0);
            w[c][0] = cvt_pk_bf16(exp2f(sc[0]), exp2f(sc[1]));
            w[c][1] = cvt_pk_bf16(exp2f(sc[2]), exp2f(sc[3]));
        }
        // in-register redistribute: target (ln,t) word m needs W[2kc+(t>>1)][m&1]
        // from row 2*(t&1)+(m>>1). combo(A,B): 32swap -> [A0 A1 B0 B1],[A2 A3 B2 B3];
        // 16swap -> [A0 A2 B0 B2],[A1 A3 B1 B3]  == (m_lo, m_hi).
#pragma unroll
        for (int kc = 0; kc < 2; ++kc) {
            unsigned a0 = w[2 * kc][0], b0 = w[2 * kc + 1][0];
            permlane32_swap(a0, b0);
            permlane16_swap(a0, b0);   // a0 = m0, b0 = m2
            unsigned a1 = w[2 * kc][1], b1 = w[2 * kc + 1][1];
            permlane32_swap(a1, b1);
            permlane16_swap(a1, b1);   // a1 = m1, b1 = m3
            union { unsigned u[4]; bf16x8 v8; } pk;
            pk.u[0] = a0; pk.u[1] = a1; pk.u[2] = b0; pk.u[3] = b1;
            bf16x8 v0 = *(const bf16x8*)(&Vs[kg2 + buf][ln][kc * 32 + quad * 8]);
            bf16x8 v1 = *(const bf16x8*)(&Vs[kg2 + buf][16 + ln][kc * 32 + quad * 8]);
            lac = __builtin_amdgcn_mfma_f32_16x16x32_bf16(pk.v8, ones, lac, 0, 0, 0);
            o0  = __builtin_amdgcn_mfma_f32_16x16x32_bf16(pk.v8, v0, o0, 0, 0, 0);
            o1  = __builtin_amdgcn_mfma_f32_16x16x32_bf16(pk.v8, v1, o1, 0, 0, 0);
        }
        if (i + 1 < 18) {
            *(uint4*)(&Ks[kg2 + (buf ^ 1)][ts >> 2][(ts & 3) * 8]) = kreg;
            *(uint4*)(&Vs[kg2 + (buf ^ 1)][ts >> 3][(ts & 7) * 8]) = vreg;
        }
    }

    // ---- epilogue: combine the two k-groups, normalize, store ----
    __syncthreads();                               // all K/V reads done; safe to alias LDS
    float (*Os)[36] = (float (*)[36])SM;           // [128][36] f32 (18432 B)
    float* Ls = (float*)(SM + 128 * 36 * 4);       // [128]
#pragma unroll
    for (int r = 0; r < 4; ++r) {
        int q = wq * 16 + quad * 4 + r;
        Os[kg * 64 + q][ln] = o0[r];
        Os[kg * 64 + q][16 + ln] = o1[r];
        if (ln == 0) Ls[kg * 64 + q] = lac[r];
    }
    __syncthreads();
    {
        int q = tid >> 3, dg = (tid & 7) * 4;
        float inv = 1.0f / (Ls[q] + Ls[64 + q]);
        float r0 = (Os[q][dg + 0] + Os[64 + q][dg + 0]) * inv;
        float r1 = (Os[q][dg + 1] + Os[64 + q][dg + 1]) * inv;
        float r2 = (Os[q][dg + 2] + Os[64 + q][dg + 2]) * inv;
        float r3 = (Os[q][dg + 3] + Os[64 + q][dg + 3]) * inv;
        *(uint2*)&y2t[((size_t)(n * SEQ) + qt * 64 + q) * 256 + h * 32 + dg] =
            make_uint2(cvt_pk_bf16(r0, r1), cvt_pk_bf16(r2, r3));
    }
}

// ---------------- Kernel 4: out GEMM (bf16 MFMA, LDS-free) + residual ----------------
__global__ __launch_bounds__(256) void out_gemm_kernel(const unsigned short* __restrict__ y2t,
                                                       const unsigned short* __restrict__ wob,
                                                       const float* __restrict__ x,
                                                       float* __restrict__ out) {
    int mt = blockIdx.x;   // 0..3
    int st = blockIdx.y;   // 0..71
    int n  = blockIdx.z;
    int tid = threadIdx.x;
    int wave = tid >> 6, lane = tid & 63;
    int ln = lane & 15, quad = lane >> 4;
    int m0 = mt * 64 + wave * 16;
    const unsigned short* Abase = wob + (size_t)(m0 + ln) * 256 + quad * 8;
    const unsigned short* Bbase = y2t + (size_t)(n * SEQ + st * 32 + ln) * 256 + quad * 8;
    f32x4 acc[2];
#pragma unroll
    for (int c = 0; c < 2; ++c) acc[c] = (f32x4){0.f, 0.f, 0.f, 0.f};
#pragma unroll
    for (int kc = 0; kc < 8; ++kc) {
        bf16x8 a = *(const bf16x8*)(Abase + kc * 32);
#pragma unroll
        for (int c = 0; c < 2; ++c) {
            bf16x8 b = *(const bf16x8*)(Bbase + (size_t)(c * 16) * 256 + kc * 32);
            acc[c] = __builtin_amdgcn_mfma_f32_16x16x32_bf16(a, b, acc[c], 0, 0, 0);
        }
    }
    const float c0f = 0.7f * 1.3130643285972254f;
    const float c1f = 0.3f * 1.3130643285972254f;
#pragma unroll
    for (int c = 0; c < 2; ++c)
#pragma unroll
        for (int r = 0; r < 4; ++r) {
            int o = m0 + quad * 4 + r;
            int s = st * 32 + c * 16 + ln;
            size_t idx = (size_t)(n * 256 + o) * SEQ + s;
            out[idx] = c0f * x[idx] + c1f * acc[c][r];
        }
}

extern "C" void kernel_launch(void* const* d_in, const int* in_sizes, int n_in,
                              void* d_out, int out_size, void* d_ws, size_t ws_size,
                              hipStream_t stream) {
    (void)in_sizes; (void)n_in; (void)out_size; (void)ws_size;
    const float* x     = (const float*)d_in[0];
    const float* w_qkv = (const float*)d_in[1];
    const float* w_out = (const float*)d_in[2];
    float* out = (float*)d_out;
    float* ws  = (float*)d_ws;
    unsigned short* wqb = (unsigned short*)(ws);             // 98304 f
    unsigned short* wob = (unsigned short*)(ws + 98304);     // 32768 f
    unsigned short* xt  = (unsigned short*)(ws + 131072);    // 589824 f (dead after qkv)
    unsigned short* y2t = (unsigned short*)(ws + 131072);    // alias of xt
    unsigned short* qn  = (unsigned short*)(ws + 720896);
    unsigned short* kn  = (unsigned short*)(ws + 1310720);
    unsigned short* vn  = (unsigned short*)(ws + 1900544);

    hipLaunchKernelGGL(prep_kernel, dim3(544), dim3(256), 0, stream,
                       w_qkv, w_out, x, wqb, wob, xt);
    hipLaunchKernelGGL(qkv_fused_kernel, dim3(8, 36, 2), dim3(256), 0, stream,
                       xt, wqb, qn, kn, vn);
    hipLaunchKernelGGL(attn_mfma_kernel, dim3(576), dim3(512), 0, stream,
                       qn, kn, vn, y2t);
    hipLaunchKernelGGL(out_gemm_kernel, dim3(4, 72, 2), dim3(256), 0, stream,
                       y2t, wob, x, out);
}